// Round 1
// baseline (226.246 us; speedup 1.0000x reference)
//
#include <hip/hip_runtime.h>
#include <hip/hip_bf16.h>

#define BB 64
#define TT 1024
#define CHN 256
#define VV 32000
#define EE 64
#define LL 128
#define NC1 250      // k1 k-chunks (250*128 = 32000)
#define KC1 128
#define TS 32        // attention t-chunks (32 t each)
#define NV5 500      // k5 v-tiles of 64 cols

typedef unsigned short u16;
typedef unsigned int u32;
typedef __attribute__((ext_vector_type(8))) short short8;
typedef __attribute__((ext_vector_type(16))) float f32x16;

__device__ __forceinline__ float fast_rcp(float x) { return __builtin_amdgcn_rcpf(x); }
__device__ __forceinline__ float tanh_fast(float y) {
    float e = __expf(2.0f * y);              // inf/0 limits give +-1 correctly
    return 1.0f - 2.0f * fast_rcp(1.0f + e);
}
__device__ __forceinline__ float sigmoid_fast(float x) {
    return fast_rcp(1.0f + __expf(-x));
}
__device__ __forceinline__ u16 f2bf(float f) {
    u32 u = __float_as_uint(f);
    return (u16)((u + 0x7fffu + ((u >> 16) & 1u)) >> 16);    // RNE
}
__device__ __forceinline__ u32 pack_bf2(float lo, float hi) {
    return (u32)f2bf(lo) | ((u32)f2bf(hi) << 16);
}
__device__ __forceinline__ float bf2f(u16 x) {
    return __uint_as_float(((u32)x) << 16);
}
// Apk index for packed-pair g (k = 2g..2g+1), batch b:
// tile tt = g>>3, kq = (g&7)>>2, reg r = g&3  ->  ((tt*2+kq)*64 + b)*4 + r
__device__ __forceinline__ size_t apk_idx(int g, int b) {
    return ((size_t)(((g >> 3) * 2 + ((g & 7) >> 2)) * 64 + b)) * 4 + (g & 3);
}

// ---------------- K1: prev_char[64,32000] @ Wc[32000,64] -> part[b][kc][e] -----------
// One block per k-chunk, ALL 64 batches (Wc read once, was twice). 512 thr, 64 KB LDS.
__global__ __launch_bounds__(512) void k1_stage1(const float* __restrict__ A,
                                                 const float* __restrict__ Wc,
                                                 float* __restrict__ part) {
    __shared__ float sW[KC1][EE];      // 32 KB
    __shared__ float sAT[KC1][64];     // 32 KB, transposed: [k][b]
    const int kc = blockIdx.x;
    const int k0 = kc * KC1;
    const int t  = threadIdx.x;

    #pragma unroll
    for (int f = t; f < 2048; f += 512)
        *(float4*)(&sW[0][0] + f * 4) = *(const float4*)(Wc + (size_t)k0 * EE + f * 4);
    {
        const int bl = t & 63;         // batch row
        const int kq = t >> 6;         // 0..7, 16 cols each
        const float* src = A + (size_t)bl * VV + k0 + kq * 16;
        #pragma unroll
        for (int j4 = 0; j4 < 4; ++j4) {
            float4 v = *(const float4*)(src + j4 * 4);
            sAT[kq * 16 + j4 * 4 + 0][bl] = v.x;
            sAT[kq * 16 + j4 * 4 + 1][bl] = v.y;
            sAT[kq * 16 + j4 * 4 + 2][bl] = v.z;
            sAT[kq * 16 + j4 * 4 + 3][bl] = v.w;
        }
    }
    __syncthreads();

    const int e  = t & 63;
    const int b0 = (t >> 6) * 8;       // 8 groups x 8 batches
    float acc[8];
    #pragma unroll
    for (int i = 0; i < 8; ++i) acc[i] = 0.0f;

    #pragma unroll 4
    for (int k = 0; k < KC1; ++k) {
        float wt = sW[k][e];
        float4 a0 = *(const float4*)&sAT[k][b0];           // wave-uniform -> broadcast
        float4 a1 = *(const float4*)&sAT[k][b0 + 4];
        acc[0] = fmaf(a0.x, wt, acc[0]);
        acc[1] = fmaf(a0.y, wt, acc[1]);
        acc[2] = fmaf(a0.z, wt, acc[2]);
        acc[3] = fmaf(a0.w, wt, acc[3]);
        acc[4] = fmaf(a1.x, wt, acc[4]);
        acc[5] = fmaf(a1.y, wt, acc[5]);
        acc[6] = fmaf(a1.z, wt, acc[6]);
        acc[7] = fmaf(a1.w, wt, acc[7]);
    }
    #pragma unroll
    for (int i = 0; i < 8; ++i)
        part[((size_t)(b0 + i) * NC1 + kc) * EE + e] = acc[i];
}

// ---------------- K2: reduce part + pcv@Wct1, z-GEMM, gates, H_tfm, Apk(h) -----------
__global__ __launch_bounds__(512) void k2_lstm(const float* __restrict__ part,
    const float* __restrict__ pcv, const float* __restrict__ state_h,
    const float* __restrict__ state_c, const float* __restrict__ Wct1,
    const float* __restrict__ lstm_kernel, const float* __restrict__ lstm_rec,
    const float* __restrict__ W_h,
    float* __restrict__ out_newh, float* __restrict__ out_newc,
    u32* __restrict__ Apk, float* __restrict__ Htfm) {
    __shared__ float red[8][EE];
    __shared__ float inp[EE];
    __shared__ float sh[LL];
    __shared__ float z[4 * LL];
    __shared__ float nh[LL];
    const int b = blockIdx.x;
    const int t = threadIdx.x;
    const int e  = t & 63;
    const int g  = t >> 6;          // 0..7

    {
        float s = 0.0f;
        #pragma unroll 4
        for (int j = g; j < NC1; j += 8)                       // contiguous 64KB window
            s += part[((size_t)b * NC1 + j) * EE + e];
        const int c0 = g * 32;
        #pragma unroll 8
        for (int c = 0; c < 32; ++c)
            s = fmaf(pcv[b * CHN + c0 + c], Wct1[(size_t)(c0 + c) * EE + e], s);
        red[g][e] = s;
    }
    __syncthreads();
    if (t < EE) {
        float s = 0.0f;
        #pragma unroll
        for (int j = 0; j < 8; ++j) s += red[j][t];
        inp[t] = s;
    } else if (t >= 64 && t < 64 + LL) {
        sh[t - 64] = state_h[b * LL + (t - 64)];
    }
    __syncthreads();
    {
        float a = 0.0f;
        #pragma unroll 8
        for (int e2 = 0; e2 < EE; ++e2) a = fmaf(inp[e2], lstm_kernel[e2 * 512 + t], a);
        #pragma unroll 8
        for (int l = 0; l < LL; ++l) a = fmaf(sh[l], lstm_rec[l * 512 + t], a);
        z[t] = a;
    }
    __syncthreads();
    if (t < LL) {
        float zi = z[t], zf = z[LL + t], zg = z[2 * LL + t], zo = z[3 * LL + t];
        float ig = sigmoid_fast(zi);
        float fg = sigmoid_fast(zf);
        float gg = tanh_fast(zg);
        float og = sigmoid_fast(zo);
        float co = state_c[b * LL + t];
        float cn = fg * co + ig * gg;
        float hn = og * tanh_fast(cn);
        out_newc[b * LL + t] = fminf(fmaxf(cn, -10.0f), 10.0f);
        out_newh[b * LL + t] = hn;
        nh[t] = hn;
    }
    __syncthreads();
    if (t < CHN) {
        float a = 0.0f;
        #pragma unroll 8
        for (int l = 0; l < LL; ++l) a = fmaf(nh[l], W_h[l * CHN + t], a);
        Htfm[b * CHN + t] = a;
    } else if (t >= CHN && t < CHN + 64) {
        const int gp = t - CHN;        // packed pairs 0..63 (h part, k=0..127)
        Apk[apk_idx(gp, b)] = pack_bf2(nh[2 * gp], nh[2 * gp + 1]);
    }
}

// ---------------- K3: attention partials per (b, ts) ---------------------------------
// TS=32 (was 16): 2048 blocks -> 32 waves/CU for HBM latency hiding on the F stream.
__global__ __launch_bounds__(256) void k3_attn(const float* __restrict__ F,
    const float* __restrict__ Htfm, const float* __restrict__ Vattn,
    float* __restrict__ pS, float* __restrict__ pW) {
    __shared__ float4 sS[256];
    __shared__ float4 sW[256];
    const int b    = blockIdx.x;
    const int ts   = blockIdx.y;
    const int lane = threadIdx.x & 63;
    const int w    = threadIdx.x >> 6;
    const int ch   = lane * 4;

    float4 h = *(const float4*)(Htfm + b * CHN + ch);
    float4 v = *(const float4*)(Vattn + ch);
    float s0 = 0, s1 = 0, s2 = 0, s3 = 0;
    float a0 = 0, a1 = 0, a2 = 0, a3 = 0;

    const float* Fp = F + ((size_t)b * TT + ts * (TT / TS) + w * 8) * CHN + ch;
    float4 cur = *(const float4*)(Fp);
    #pragma unroll
    for (int t = 0; t < 8; ++t) {
        float4 nxt;
        if (t < 7) nxt = *(const float4*)(Fp + (size_t)(t + 1) * CHN);
        float e0 = __expf(v.x * tanh_fast(h.x + cur.x));
        float e1 = __expf(v.y * tanh_fast(h.y + cur.y));
        float e2 = __expf(v.z * tanh_fast(h.z + cur.z));
        float e3 = __expf(v.w * tanh_fast(h.w + cur.w));
        s0 += e0; s1 += e1; s2 += e2; s3 += e3;
        a0 = fmaf(e0, cur.x, a0); a1 = fmaf(e1, cur.y, a1);
        a2 = fmaf(e2, cur.z, a2); a3 = fmaf(e3, cur.w, a3);
        cur = nxt;
    }
    sS[threadIdx.x] = make_float4(s0, s1, s2, s3);
    sW[threadIdx.x] = make_float4(a0, a1, a2, a3);
    __syncthreads();
    if (threadIdx.x < 64) {
        float4 S = sS[threadIdx.x];
        float4 W = sW[threadIdx.x];
        #pragma unroll
        for (int j = 1; j < 4; ++j) {
            float4 s = sS[j * 64 + threadIdx.x];
            float4 q = sW[j * 64 + threadIdx.x];
            S.x += s.x; S.y += s.y; S.z += s.z; S.w += s.w;
            W.x += q.x; W.y += q.y; W.z += q.z; W.w += q.w;
        }
        int base = (b * TS + ts) * CHN + threadIdx.x * 4;
        *(float4*)(pS + base) = S;
        *(float4*)(pW + base) = W;
    }
}

// ---------------- K4: reduce TS chunks -> c_t + Apk(c) -------------------------------
__global__ __launch_bounds__(256) void k4_combine(const float* __restrict__ pS,
    const float* __restrict__ pW, float* __restrict__ out_ct, u32* __restrict__ Apk) {
    __shared__ float sc[CHN];
    const int b = blockIdx.x;
    const int ch = threadIdx.x;
    float S = 0.0f, W = 0.0f;
    #pragma unroll
    for (int j = 0; j < TS; ++j) {
        int idx = (b * TS + j) * CHN + ch;
        S += pS[idx];
        W += pW[idx];
    }
    float c = W / S;
    out_ct[b * CHN + ch] = c;
    sc[ch] = c;
    __syncthreads();
    if (ch < 128)                      // packed pairs 64..191 (c part, k=128..383)
        Apk[apk_idx(64 + ch, b)] = pack_bf2(sc[2 * ch], sc[2 * ch + 1]);
}

// ---------------- K5: MFMA bf16 logits -> bf16 exp + per-block row partials ----------
// grid (500 v-tiles of 64 cols) x 256 thr. Weights now read EXACTLY ONCE (was twice):
// 4 waves = (v-half 0/1) x (b-half 0/1); the two waves per v-half issue identical
// weight addresses back-to-back on the same CU -> second is an L1/L2 hit.
// W stream f32 -> truncated bf16, 2-tile-deep prefetch (indices static under unroll).
__global__ __launch_bounds__(256) void k5_logits(const float* __restrict__ Wo,
    const float* __restrict__ Wct2, const u32* __restrict__ Apk,
    u16* __restrict__ expb, float* __restrict__ psum) {
    __shared__ float rp[4][32];
    const int t    = threadIdx.x;
    const int lane = t & 63;
    const int wv   = t >> 6;           // 0..3
    const int m    = lane & 31;        // local b (A row / C col)
    const int kq   = lane >> 5;        // k-half select
    const int vt   = blockIdx.x;       // 0..499
    const int n0   = vt * 64 + (wv >> 1) * 32;
    const int gb0  = (wv & 1) * 32;

    uint4 af[24];
    #pragma unroll
    for (int tt = 0; tt < 24; ++tt)
        af[tt] = *(const uint4*)&Apk[((size_t)((tt * 2 + kq) * 64) + gb0 + m) * 4];

    f32x16 acc = {0.0f, 0.0f, 0.0f, 0.0f, 0.0f, 0.0f, 0.0f, 0.0f,
                  0.0f, 0.0f, 0.0f, 0.0f, 0.0f, 0.0f, 0.0f, 0.0f};

    float wbuf[3][8];
    #pragma unroll
    for (int pf = 0; pf < 2; ++pf) {   // prefetch tiles 0,1 (rows < 40 -> always Wo)
        const float* c0 = Wo + (size_t)(pf * 16 + kq * 8) * VV + n0 + m;
        #pragma unroll
        for (int j = 0; j < 8; ++j) wbuf[pf][j] = c0[(size_t)j * VV];
    }

    #pragma unroll
    for (int tt = 0; tt < 24; ++tt) {
        if (tt < 22) {                 // prefetch tile tt+2
            const int kn = (tt + 2) * 16 + kq * 8;
            const float* cn = (kn < LL ? Wo + (size_t)kn * VV
                                       : Wct2 + (size_t)(kn - LL) * VV) + n0 + m;
            #pragma unroll
            for (int j = 0; j < 8; ++j) wbuf[(tt + 2) % 3][j] = cn[(size_t)j * VV];
        }
        short8 a, b;
        u32 ax = af[tt].x, ay = af[tt].y, az = af[tt].z, aw = af[tt].w;
        #pragma unroll
        for (int r = 0; r < 4; ++r) {
            u32 lo = __float_as_uint(wbuf[tt % 3][2 * r]);
            u32 hi = __float_as_uint(wbuf[tt % 3][2 * r + 1]);
            u32 bp = (lo >> 16) | (hi & 0xffff0000u);       // truncate-to-bf16 pair
            u32 ap = (r == 0) ? ax : (r == 1) ? ay : (r == 2) ? az : aw;
            a[2 * r]     = (short)(ap & 0xffff);
            a[2 * r + 1] = (short)(ap >> 16);
            b[2 * r]     = (short)(bp & 0xffff);
            b[2 * r + 1] = (short)(bp >> 16);
        }
        acc = __builtin_amdgcn_mfma_f32_32x32x16_bf16(a, b, acc, 0, 0, 0);
    }

    // epilogue: exp (f32), bf16 store, row partials. C/D: col=m, row=(r&3)+8(r>>2)+4kq
    float ex[16];
    #pragma unroll
    for (int r = 0; r < 16; ++r) {
        const int row = (r & 3) + 8 * (r >> 2) + 4 * kq;
        ex[r] = __expf(acc[r]);                             // logits bounded ~|4|
        expb[(size_t)(gb0 + row) * VV + n0 + m] = f2bf(ex[r]);
    }
    #pragma unroll
    for (int r = 0; r < 16; ++r) {                          // sum across 32 cols
        float s = ex[r];
        s += __shfl_xor(s, 1, 64);  s += __shfl_xor(s, 2, 64);
        s += __shfl_xor(s, 4, 64);  s += __shfl_xor(s, 8, 64);
        s += __shfl_xor(s, 16, 64);
        ex[r] = s;
    }
    if (m == 0) {                                           // lanes 0 and 32
        #pragma unroll
        for (int r = 0; r < 16; ++r)
            rp[wv][(r & 3) + 8 * (r >> 2) + 4 * kq] = ex[r];
    }
    __syncthreads();
    if (t < 64) {                      // b<32: waves 0+2 ; b>=32: waves 1+3
        const int hb = t >> 5, r = t & 31;
        psum[(size_t)vt * BB + t] = rp[hb][r] + rp[2 + hb][r];
    }
}

// ---------------- K5c: rowsum (in-block) + normalize bf16 exp -> f32 O ---------------
// grid (64 rows, 8 segs of 4000 v) x 256 thr.
__global__ __launch_bounds__(256) void k5c_norm(const u16* __restrict__ expb,
    const float* __restrict__ psum, float* __restrict__ O) {
    __shared__ float red[256];
    const int b   = blockIdx.x;
    const int seg = blockIdx.y;
    const int t   = threadIdx.x;

    float s = psum[(size_t)t * BB + b];                     // t < 256 < NV5
    if (t + 256 < NV5) s += psum[(size_t)(t + 256) * BB + b];
    red[t] = s;
    __syncthreads();
    #pragma unroll
    for (int off = 128; off > 0; off >>= 1) {
        if (t < off) red[t] += red[t + off];
        __syncthreads();
    }
    const float inv = fast_rcp(red[0]);

    const u16* src = expb + (size_t)b * VV + seg * 4000;
    float* dst     = O + (size_t)b * VV + seg * 4000;
    #pragma unroll 2
    for (int i = t; i < 1000; i += 256) {            // 1000 x (4 bf16)
        uint2 pk = *(const uint2*)(src + i * 4);
        float4 f;
        f.x = bf2f((u16)(pk.x & 0xffff)) * inv;
        f.y = bf2f((u16)(pk.x >> 16)) * inv;
        f.z = bf2f((u16)(pk.y & 0xffff)) * inv;
        f.w = bf2f((u16)(pk.y >> 16)) * inv;
        *(float4*)(dst + i * 4) = f;
    }
}

extern "C" void kernel_launch(void* const* d_in, const int* in_sizes, int n_in,
                              void* d_out, int out_size, void* d_ws, size_t ws_size,
                              hipStream_t stream) {
    (void)in_sizes; (void)n_in; (void)out_size; (void)ws_size;
    const float* pcv       = (const float*)d_in[0];
    const float* F         = (const float*)d_in[1];
    const float* prev_char = (const float*)d_in[2];
    const float* state_h   = (const float*)d_in[3];
    const float* state_c   = (const float*)d_in[4];
    const float* Wc        = (const float*)d_in[5];
    const float* Wct1      = (const float*)d_in[6];
    const float* Wo        = (const float*)d_in[7];
    const float* Wct2      = (const float*)d_in[8];
    const float* lstm_k    = (const float*)d_in[9];
    const float* lstm_r    = (const float*)d_in[10];
    const float* W_h       = (const float*)d_in[11];
    const float* Vattn     = (const float*)d_in[12];

    // outputs: float32, concatenated flat in return order
    float* outO  = (float*)d_out;                  // [64][32000]
    float* outCt = outO + (size_t)BB * VV;         // [64][256]
    float* outH  = outCt + (size_t)BB * CHN;       // [64][128]
    float* outC  = outH + (size_t)BB * LL;         // [64][128]

    float* ws     = (float*)d_ws;
    float* part   = ws;                            // 250*64*64 = 1,024,000 f
    float* pS     = part + (size_t)NC1 * BB * EE;  // 64*32*256 = 524,288 f
    float* pW     = pS + (size_t)BB * TS * CHN;    // 524,288 f
    float* Htfm   = pW + (size_t)BB * TS * CHN;    // 16,384 f
    float* psum   = Htfm + (size_t)BB * CHN;       // 500*64 = 32,000 f
    u32*   Apk    = (u32*)(psum + (size_t)NV5 * BB);   // 24*2*64*4 = 12,288 u32
    u16*   expb   = (u16*)(Apk + 12288);           // 64*32000 u16 = 4.1 MB

    hipLaunchKernelGGL(k1_stage1, dim3(NC1), dim3(512), 0, stream, prev_char, Wc, part);
    hipLaunchKernelGGL(k2_lstm, dim3(BB), dim3(512), 0, stream, part, pcv, state_h,
                       state_c, Wct1, lstm_k, lstm_r, W_h, outH, outC, Apk, Htfm);
    hipLaunchKernelGGL(k3_attn, dim3(BB, TS), dim3(256), 0, stream, F, Htfm, Vattn, pS, pW);
    hipLaunchKernelGGL(k4_combine, dim3(BB), dim3(256), 0, stream, pS, pW, outCt, Apk);
    hipLaunchKernelGGL(k5_logits, dim3(NV5), dim3(256), 0, stream, Wo, Wct2, Apk, expb, psum);
    hipLaunchKernelGGL(k5c_norm, dim3(BB, 8), dim3(256), 0, stream, expb, psum, outO);
}